// Round 1
// baseline (243.588 us; speedup 1.0000x reference)
//
#include <hip/hip_runtime.h>
#include <hip/hip_cooperative_groups.h>
#include <math.h>

namespace cg = cooperative_groups;

#define SS 8192
#define HH 2048
#define NBLK 512
#define NTHR 256

// ws layout: v2 = ws[0..2048) (8 KB, zeroed by memset), scores = ws[2048..10240) (32 KB)

__global__ __launch_bounds__(NTHR, 2) void fused_kernel(
    const float* __restrict__ enc,
    const float* __restrict__ W,
    const float* __restrict__ w,
    float* __restrict__ out,
    float* __restrict__ v2,
    float* __restrict__ sc)
{
    cg::grid_group grid = cg::this_grid();
    const int b = blockIdx.x;
    const int t = threadIdx.x;

    // ---- Phase 1: v2[col] = sum_j w[j] * W[j, HH+col] ----
    // 512 blocks: 8 col-chunks (256 cols) x 64 row-chunks (32 rows).
    {
        const int c    = b & 7;
        const int r    = b >> 3;
        const int col  = c * 256 + t;
        const int row0 = r * 32;
        const float* base = W + (size_t)row0 * (2 * HH) + HH + col;
        float acc = 0.0f;
#pragma unroll 8
        for (int j = 0; j < 32; ++j)
            acc += w[row0 + j] * base[(size_t)j * (2 * HH)];
        atomicAdd(&v2[col], acc);
    }

    grid.sync();

    // ---- Phase 2: sc[row] = enc[row,:] . v2 ----
    // 512 blocks x 4 waves; each wave: v2 fragment in regs, 4 rows.
    {
        const int wave = t >> 6;
        const int lane = t & 63;
        const float4* v = (const float4*)v2;
        float4 vf[8];
#pragma unroll
        for (int i = 0; i < 8; ++i) vf[i] = v[lane + i * 64];

        const int row_base = b * 16 + wave * 4;
#pragma unroll
        for (int rr = 0; rr < 4; ++rr) {
            const int row = row_base + rr;
            const float4* e = (const float4*)(enc + (size_t)row * HH);
            float acc = 0.0f;
#pragma unroll
            for (int i = 0; i < 8; ++i) {
                float4 a = e[lane + i * 64];
                acc += a.x * vf[i].x + a.y * vf[i].y
                     + a.z * vf[i].z + a.w * vf[i].w;
            }
#pragma unroll
            for (int off = 32; off > 0; off >>= 1)
                acc += __shfl_down(acc, off);
            if (lane == 0) sc[row] = acc;
        }
    }

    grid.sync();

    // ---- Phase 3: softmax. Every block redundantly reduces all 8192
    // scores (L2-resident), writes only its own 16-element slice to out.
    // sc is read-only here, out is write-only -> no cross-block race.
    {
        __shared__ float red[4];
        const int lane = t & 63;
        const int wid  = t >> 6;

        float vals[32];
        float m = -INFINITY;
#pragma unroll
        for (int i = 0; i < 32; ++i) {
            vals[i] = sc[t + i * 256];
            m = fmaxf(m, vals[i]);
        }
#pragma unroll
        for (int off = 1; off < 64; off <<= 1)
            m = fmaxf(m, __shfl_xor(m, off));
        if (lane == 0) red[wid] = m;
        __syncthreads();
        m = fmaxf(fmaxf(red[0], red[1]), fmaxf(red[2], red[3]));

        float s = 0.0f;
#pragma unroll
        for (int i = 0; i < 32; ++i)
            s += __expf(vals[i] - m);
#pragma unroll
        for (int off = 1; off < 64; off <<= 1)
            s += __shfl_xor(s, off);
        __syncthreads();                    // done reading red for max
        if (lane == 0) red[wid] = s;
        __syncthreads();
        const float inv = 1.0f / (red[0] + red[1] + red[2] + red[3]);

        if (t < 16) {
            const int e = 16 * b + t;
            out[e] = __expf(sc[e] - m) * inv;
        }
    }
}

extern "C" void kernel_launch(void* const* d_in, const int* in_sizes, int n_in,
                              void* d_out, int out_size, void* d_ws, size_t ws_size,
                              hipStream_t stream) {
    const float* enc   = (const float*)d_in[0];  // (S,1,H) -> (S,H)
    // d_in[1] = hidden : constant score shift -> cancels in softmax
    const float* W_att = (const float*)d_in[2];  // (H, 2H)
    // d_in[3] = b_att  : constant shift -> cancels
    const float* w     = (const float*)d_in[4];  // (1, H)

    float* out = (float*)d_out;                  // 8192 floats (1,1,S)
    float* v2  = (float*)d_ws;                   // 2048 floats
    float* sc  = v2 + HH;                        // 8192 floats (raw scores)

    hipMemsetAsync(v2, 0, HH * sizeof(float), stream);

    void* args[] = { (void*)&enc, (void*)&W_att, (void*)&w,
                     (void*)&out, (void*)&v2, (void*)&sc };
    hipLaunchCooperativeKernel((void*)fused_kernel, dim3(NBLK), dim3(NTHR),
                               args, 0, stream);
}

// Round 2
// 126.044 us; speedup vs baseline: 1.9326x; 1.9326x over previous
//
#include <hip/hip_runtime.h>
#include <math.h>

#define SS 8192
#define HH 2048
// W_att is (H, 2H) row-major, row stride 2*HH = 4096 floats.
// ws layout: v2 = ws[0..2048) (8 KB, zeroed by memset), sc = ws[2048..10240) (32 KB)

// grid (2, 64), block 256. blockIdx.x picks 1024 cols (256 thr x float4),
// blockIdx.y picks 32 rows. v2[col] += sum_j w[j] * W[j, HH+col].
// 32 independent float4 loads per thread -> deep MLP; 16 MB total, BW-bound.
__global__ void colsum_kernel(const float* __restrict__ W,
                              const float* __restrict__ w,
                              float* __restrict__ v2) {
    const int t       = threadIdx.x;
    const int colBase = blockIdx.x * 1024;
    const int row0    = blockIdx.y * 32;
    const float4* base =
        (const float4*)(W + (size_t)row0 * (2 * HH) + HH + colBase) + t;
    float4 acc = {0.f, 0.f, 0.f, 0.f};
#pragma unroll
    for (int j = 0; j < 32; ++j) {
        float4 a = base[(size_t)j * ((2 * HH) / 4)];
        float wj = w[row0 + j];                 // block-uniform -> s_load
        acc.x += wj * a.x; acc.y += wj * a.y;
        acc.z += wj * a.z; acc.w += wj * a.w;
    }
    float* dst = v2 + colBase + t * 4;
    atomicAdd(dst + 0, acc.x);
    atomicAdd(dst + 1, acc.y);
    atomicAdd(dst + 2, acc.z);
    atomicAdd(dst + 3, acc.w);
}

// grid 1024, block 256 = 4 waves. Each wave: v2 in registers (vf[8]), 2 rows.
// 1024 blocks -> 4/CU -> 16 waves/CU; 64 MB of enc, should run near HBM BW.
__global__ __launch_bounds__(256) void rowdot_kernel(
    const float* __restrict__ enc,
    const float* __restrict__ v2,
    float* __restrict__ sc)
{
    const int wave = threadIdx.x >> 6;
    const int lane = threadIdx.x & 63;
    const float4* v = (const float4*)v2;
    float4 vf[8];
#pragma unroll
    for (int i = 0; i < 8; ++i) vf[i] = v[lane + i * 64];

    const int row_base = blockIdx.x * 8 + wave * 2;
#pragma unroll
    for (int rr = 0; rr < 2; ++rr) {
        const int row = row_base + rr;
        const float4* e = (const float4*)(enc + (size_t)row * HH);
        float acc = 0.0f;
#pragma unroll
        for (int i = 0; i < 8; ++i) {
            float4 a = e[lane + i * 64];
            acc += a.x * vf[i].x + a.y * vf[i].y
                 + a.z * vf[i].z + a.w * vf[i].w;
        }
#pragma unroll
        for (int off = 32; off > 0; off >>= 1)
            acc += __shfl_down(acc, off);
        if (lane == 0) sc[row] = acc;
    }
}

// grid 512, block 256. Every block redundantly reduces all 8192 scores
// (32 KB, L2-resident) and writes only its own 16-element output slice.
// sc read-only, out write-only -> no cross-block dependency, no coop launch.
__global__ __launch_bounds__(256) void softmax_kernel(
    const float* __restrict__ sc,
    float* __restrict__ out)
{
    __shared__ float red[4];
    const int t    = threadIdx.x;
    const int lane = t & 63;
    const int wid  = t >> 6;

    float vals[32];
    float m = -INFINITY;
#pragma unroll
    for (int i = 0; i < 32; ++i) {
        vals[i] = sc[t + i * 256];
        m = fmaxf(m, vals[i]);
    }
#pragma unroll
    for (int off = 1; off < 64; off <<= 1)
        m = fmaxf(m, __shfl_xor(m, off));
    if (lane == 0) red[wid] = m;
    __syncthreads();
    m = fmaxf(fmaxf(red[0], red[1]), fmaxf(red[2], red[3]));

    float s = 0.0f;
#pragma unroll
    for (int i = 0; i < 32; ++i)
        s += __expf(vals[i] - m);
#pragma unroll
    for (int off = 1; off < 64; off <<= 1)
        s += __shfl_xor(s, off);
    __syncthreads();                 // everyone done reading red (max)
    if (lane == 0) red[wid] = s;
    __syncthreads();
    const float inv = 1.0f / (red[0] + red[1] + red[2] + red[3]);

    if (t < 16) {
        const int e = blockIdx.x * 16 + t;
        out[e] = __expf(sc[e] - m) * inv;
    }
}

extern "C" void kernel_launch(void* const* d_in, const int* in_sizes, int n_in,
                              void* d_out, int out_size, void* d_ws, size_t ws_size,
                              hipStream_t stream) {
    const float* enc   = (const float*)d_in[0];  // (S,1,H) -> (S,H)
    // d_in[1] = hidden : constant score shift -> cancels in softmax
    const float* W_att = (const float*)d_in[2];  // (H, 2H)
    // d_in[3] = b_att  : constant shift -> cancels
    const float* w     = (const float*)d_in[4];  // (1, H)

    float* out = (float*)d_out;                  // 8192 floats (1,1,S)
    float* v2  = (float*)d_ws;                   // 2048 floats
    float* sc  = v2 + HH;                        // 8192 floats (raw scores)

    hipMemsetAsync(v2, 0, HH * sizeof(float), stream);
    hipLaunchKernelGGL(colsum_kernel,  dim3(2, 64), dim3(256), 0, stream,
                       W_att, w, v2);
    hipLaunchKernelGGL(rowdot_kernel,  dim3(1024), dim3(256), 0, stream,
                       enc, v2, sc);
    hipLaunchKernelGGL(softmax_kernel, dim3(512),  dim3(256), 0, stream,
                       sc, out);
}

// Round 3
// 123.385 us; speedup vs baseline: 1.9742x; 1.0216x over previous
//
#include <hip/hip_runtime.h>
#include <math.h>

#define SS 8192
#define HH 2048
#define NP 32          // number of row-chunk partials
// W_att is (H, 2H) row-major, row stride 2*HH = 4096 floats.
// ws layout: partial = ws[0 .. NP*2048)  (256 KB, no zero-init needed)
//            sc      = ws[NP*2048 .. NP*2048+8192)  (32 KB raw scores)

// grid (8, NP) = 256 blocks, block 256. Block (bx,by): cols bx*256+t,
// rows by*64 .. by*64+63. Writes its OWN partial slice -> no atomics, no memset.
__global__ __launch_bounds__(256) void colsum_partial(
    const float* __restrict__ W,
    const float* __restrict__ w,
    float* __restrict__ partial)
{
    const int t    = threadIdx.x;
    const int col  = blockIdx.x * 256 + t;
    const int row0 = blockIdx.y * 64;
    const float* base = W + (size_t)row0 * (2 * HH) + HH + col;
    float acc = 0.0f;
#pragma unroll 8
    for (int j = 0; j < 64; ++j)
        acc += w[row0 + j] * base[(size_t)j * (2 * HH)];
    partial[(size_t)blockIdx.y * HH + col] = acc;
}

// grid 512, block 512 = 8 waves. Phase A: reduce NP partials -> v2 in LDS
// (L2-resident, 256 KB/block, ~4 us aggregate). Phase B: each wave holds v2
// fragment in regs and computes 2 rows; block covers 16 rows.
__global__ __launch_bounds__(512) void rowdot_kernel(
    const float* __restrict__ enc,
    const float* __restrict__ partial,
    float* __restrict__ sc)
{
    __shared__ float4 v2f[512];
    const int t = threadIdx.x;

    // Phase A: thread t reduces cols 4t..4t+3 across NP partials.
    {
        const float4* p = (const float4*)partial;   // [NP][512] float4s
        float4 a = p[t];
#pragma unroll
        for (int j = 1; j < NP; ++j) {
            float4 b = p[t + j * 512];
            a.x += b.x; a.y += b.y; a.z += b.z; a.w += b.w;
        }
        v2f[t] = a;
    }
    __syncthreads();

    // Phase B
    const int wave = t >> 6;
    const int lane = t & 63;
    float4 vf[8];
#pragma unroll
    for (int i = 0; i < 8; ++i) vf[i] = v2f[lane + i * 64];

    const int row_base = blockIdx.x * 16 + wave * 2;
#pragma unroll
    for (int rr = 0; rr < 2; ++rr) {
        const int row = row_base + rr;
        const float4* e = (const float4*)(enc + (size_t)row * HH);
        float acc = 0.0f;
#pragma unroll
        for (int i = 0; i < 8; ++i) {
            float4 a = e[lane + i * 64];
            acc += a.x * vf[i].x + a.y * vf[i].y
                 + a.z * vf[i].z + a.w * vf[i].w;
        }
#pragma unroll
        for (int off = 32; off > 0; off >>= 1)
            acc += __shfl_down(acc, off);
        if (lane == 0) sc[row] = acc;
    }
}

// grid 512, block 256. Every block redundantly reduces all 8192 scores
// (32 KB, L2-resident) and writes only its own 16-element output slice.
__global__ __launch_bounds__(256) void softmax_kernel(
    const float* __restrict__ sc,
    float* __restrict__ out)
{
    __shared__ float red[4];
    const int t    = threadIdx.x;
    const int lane = t & 63;
    const int wid  = t >> 6;

    float vals[32];
    float m = -INFINITY;
#pragma unroll
    for (int i = 0; i < 32; ++i) {
        vals[i] = sc[t + i * 256];
        m = fmaxf(m, vals[i]);
    }
#pragma unroll
    for (int off = 1; off < 64; off <<= 1)
        m = fmaxf(m, __shfl_xor(m, off));
    if (lane == 0) red[wid] = m;
    __syncthreads();
    m = fmaxf(fmaxf(red[0], red[1]), fmaxf(red[2], red[3]));

    float s = 0.0f;
#pragma unroll
    for (int i = 0; i < 32; ++i)
        s += __expf(vals[i] - m);
#pragma unroll
    for (int off = 1; off < 64; off <<= 1)
        s += __shfl_xor(s, off);
    __syncthreads();                 // everyone done reading red (max)
    if (lane == 0) red[wid] = s;
    __syncthreads();
    const float inv = 1.0f / (red[0] + red[1] + red[2] + red[3]);

    if (t < 16) {
        const int e = blockIdx.x * 16 + t;
        out[e] = __expf(sc[e] - m) * inv;
    }
}

extern "C" void kernel_launch(void* const* d_in, const int* in_sizes, int n_in,
                              void* d_out, int out_size, void* d_ws, size_t ws_size,
                              hipStream_t stream) {
    const float* enc   = (const float*)d_in[0];  // (S,1,H) -> (S,H)
    // d_in[1] = hidden : constant score shift -> cancels in softmax
    const float* W_att = (const float*)d_in[2];  // (H, 2H)
    // d_in[3] = b_att  : constant shift -> cancels
    const float* w     = (const float*)d_in[4];  // (1, H)

    float* out     = (float*)d_out;              // 8192 floats (1,1,S)
    float* partial = (float*)d_ws;               // NP*2048 floats
    float* sc      = partial + NP * HH;          // 8192 floats (raw scores)

    hipLaunchKernelGGL(colsum_partial, dim3(8, NP), dim3(256), 0, stream,
                       W_att, w, partial);
    hipLaunchKernelGGL(rowdot_kernel,  dim3(512),   dim3(512), 0, stream,
                       enc, partial, sc);
    hipLaunchKernelGGL(softmax_kernel, dim3(512),   dim3(256), 0, stream,
                       sc, out);
}